// Round 1
// baseline (16639.891 us; speedup 1.0000x reference)
//
#include <hip/hip_runtime.h>

typedef _Float16 f16;
typedef f16 f16x2 __attribute__((ext_vector_type(2)));
typedef f16 f16x8 __attribute__((ext_vector_type(8)));
typedef float f32x4 __attribute__((ext_vector_type(4)));

#define TT 1024
#define BB 32
#define DD 1024
#define RR 256

__device__ __forceinline__ float dot2f(f16x2 a, f16x2 b, float c) {
#if __has_builtin(__builtin_amdgcn_fdot2)
    return __builtin_amdgcn_fdot2(a, b, c, false);
#else
    return c + (float)a[0] * (float)b[0] + (float)a[1] * (float)b[1];
#endif
}

__device__ __forceinline__ float sigm_f(float x) { return 1.0f / (1.0f + __expf(-x)); }
__device__ __forceinline__ float tanh_f(float x) { return 1.0f - 2.0f / (1.0f + __expf(2.0f * x)); }

// ---------------------------------------------------------------------------
// Kernel 1: fused pre-GEMM.  ax = x @ W_alpha^T + b_alpha ; wx = x @ W_x^T + b
// A = x [32768 x 1024] f32 row-major; W [1024 x 1024] row-major (B^T form:
// out[m,n] = sum_k A[m,k] * W[n,k]).  f32 -> f16 conversion during LDS staging.
// Block: 256 threads (4 waves), tile 64x64, BK=32 (one mfma_16x16x32 per K-step).
// ---------------------------------------------------------------------------
__global__ __launch_bounds__(256)
void fused_pregemm(const float* __restrict__ X, const float* __restrict__ Wa,
                   const float* __restrict__ Wx, const float* __restrict__ ba,
                   const float* __restrict__ bb, f16* __restrict__ axo,
                   f16* __restrict__ wxo)
{
    __shared__ __align__(16) f16 lA[64][40];   // +8 pad: break power-of-2 stride
    __shared__ __align__(16) f16 lB[64][40];
    __shared__ __align__(16) f16 lC[64][40];

    const int tid = threadIdx.x;
    const int w   = tid >> 6;        // wave 0..3 -> m-strip
    const int l   = tid & 63;
    const int la  = l & 15;          // lane row/col within 16x16 tile
    const int qd  = l >> 4;          // quad 0..3
    const int m0  = blockIdx.x * 64; // x fastest -> full M pass per n-col (L3 reuse)
    const int n0  = blockIdx.y * 64;
    const int sr  = tid >> 2;        // staging row 0..63
    const int sk  = (tid & 3) * 8;   // staging k offset {0,8,16,24}

    f32x4 accA[4] = {};
    f32x4 accX[4] = {};

    for (int k0 = 0; k0 < DD; k0 += 32) {
        // ---- stage f32 global -> f16 LDS (8 values per thread per matrix)
        {
            const float* pX = X + (size_t)(m0 + sr) * DD + k0 + sk;
            float4 v0 = *(const float4*)pX;
            float4 v1 = *(const float4*)(pX + 4);
            f16x8 x8 = {(f16)v0.x, (f16)v0.y, (f16)v0.z, (f16)v0.w,
                        (f16)v1.x, (f16)v1.y, (f16)v1.z, (f16)v1.w};
            *(f16x8*)&lA[sr][sk] = x8;

            const float* pA = Wa + (size_t)(n0 + sr) * DD + k0 + sk;
            v0 = *(const float4*)pA;
            v1 = *(const float4*)(pA + 4);
            f16x8 a8 = {(f16)v0.x, (f16)v0.y, (f16)v0.z, (f16)v0.w,
                        (f16)v1.x, (f16)v1.y, (f16)v1.z, (f16)v1.w};
            *(f16x8*)&lB[sr][sk] = a8;

            const float* pW = Wx + (size_t)(n0 + sr) * DD + k0 + sk;
            v0 = *(const float4*)pW;
            v1 = *(const float4*)(pW + 4);
            f16x8 w8 = {(f16)v0.x, (f16)v0.y, (f16)v0.z, (f16)v0.w,
                        (f16)v1.x, (f16)v1.y, (f16)v1.z, (f16)v1.w};
            *(f16x8*)&lC[sr][sk] = w8;
        }
        __syncthreads();

        // ---- MFMA: A-frag lane mapping A[m=la][k=qd*8+j]
        f16x8 af = *(const f16x8*)&lA[16 * w + la][qd * 8];
        #pragma unroll
        for (int c = 0; c < 4; c++) {
            f16x8 b1 = *(const f16x8*)&lB[16 * c + la][qd * 8];
            f16x8 b2 = *(const f16x8*)&lC[16 * c + la][qd * 8];
            accA[c] = __builtin_amdgcn_mfma_f32_16x16x32_f16(af, b1, accA[c], 0, 0, 0);
            accX[c] = __builtin_amdgcn_mfma_f32_16x16x32_f16(af, b2, accX[c], 0, 0, 0);
        }
        __syncthreads();
    }

    // ---- epilogue: D lane mapping row=qd*4+r, col=la (verified m89/m91 layout)
    #pragma unroll
    for (int c = 0; c < 4; c++) {
        const int n = n0 + 16 * c + la;
        const float bav = ba[n];
        const float bbv = bb[n];
        #pragma unroll
        for (int r = 0; r < 4; r++) {
            const int m = m0 + 16 * w + qd * 4 + r;
            axo[(size_t)m * DD + n] = (f16)(accA[c][r] + bav);
            wxo[(size_t)m * DD + n] = (f16)(accX[c][r] + bbv);
        }
    }
}

// ---------------------------------------------------------------------------
// Kernel 2: sequential scan.  32 WGs (one per batch), 1024 threads, no
// cross-WG sync.  V,U register-resident as f16 pairs (256 VGPRs of weights
// per thread), fdot2 f32-accumulate.  h kept f32 (blend path) + f16 (matvec).
//   stage1: p[r] = sum_d h[d] V[r,d]   thread (s=tid>>6, q=tid&63) owns
//           V[4q..4q+4)[64s..64s+64)  -> 4 partials, LDS-reduced over 16 s.
//   stage2: u[e] = sum_r p[r] U[e,r]   thread (e2=tid>>1, z=tid&1) owns
//           U[2e2..2e2+2)[128z..128z+128) -> 2 partials, 2-way combine.
// ---------------------------------------------------------------------------
__global__ __launch_bounds__(1024, 4)
void rnn_scan(const f16* __restrict__ ax, const f16* __restrict__ wx,
              const float* __restrict__ V, const float* __restrict__ U,
              const float* __restrict__ h0, float* __restrict__ out,
              float* __restrict__ hout)
{
    const int b   = blockIdx.x;
    const int tid = threadIdx.x;
    const int s   = tid >> 6;   // d-slice 0..15 (== wave id: broadcast LDS reads)
    const int q   = tid & 63;   // r-quad
    const int e2  = tid >> 1;   // e-pair 0..511
    const int z   = tid & 1;    // r-half

    __shared__ __align__(16) f16 h2[DD];       // h as f16 (matvec input)
    __shared__ float hf[DD];                   // h as f32 (blend path)
    __shared__ float part[16][RR];             // stage1 partials [s][r]
    __shared__ __align__(16) f16 pl[RR];       // p as f16
    __shared__ float up[DD][2];                // stage2 partials [e][z]

    // ---- load weights into registers (once; 32 WGs x 2MB f32 = 64MB reads)
    f16x2 wv[4][32];
    #pragma unroll
    for (int j = 0; j < 4; j++) {
        const float2* vr = (const float2*)(V + (size_t)(4 * q + j) * DD + 64 * s);
        #pragma unroll
        for (int i = 0; i < 32; i++) {
            float2 t = vr[i];
            f16x2 p2 = {(f16)t.x, (f16)t.y};
            wv[j][i] = p2;
        }
    }
    f16x2 wu[2][64];
    #pragma unroll
    for (int j = 0; j < 2; j++) {
        const float2* ur = (const float2*)(U + (size_t)(2 * e2 + j) * RR + 128 * z);
        #pragma unroll
        for (int i = 0; i < 64; i++) {
            float2 t = ur[i];
            f16x2 p2 = {(f16)t.x, (f16)t.y};
            wu[j][i] = p2;
        }
    }

    // ---- init h state; emit h[0] = h0
    const float h0v = h0[(size_t)b * DD + tid];
    hf[tid] = h0v;
    h2[tid] = (f16)h0v;
    hout[(size_t)b * DD + tid] = h0v;

    const f16* axp  = ax  + (size_t)b * DD + tid;
    const f16* wxp  = wx  + (size_t)b * DD + tid;
    float*     outp = out + (size_t)b * DD + tid;
    float*     houtp = hout + (size_t)BB * DD + (size_t)b * DD + tid;

    __syncthreads();

    #pragma unroll 1
    for (int t = 0; t < TT; t++) {
        // ---- stage 1: partial p over my d-slice (h reads are wave-broadcast)
        const f16x8* hsl = (const f16x8*)(h2 + 64 * s);
        float acc[4] = {0.f, 0.f, 0.f, 0.f};
        #pragma unroll
        for (int i = 0; i < 8; i++) {
            f16x8 hv = hsl[i];
            f16x2 hp[4];
            hp[0][0] = hv[0]; hp[0][1] = hv[1];
            hp[1][0] = hv[2]; hp[1][1] = hv[3];
            hp[2][0] = hv[4]; hp[2][1] = hv[5];
            hp[3][0] = hv[6]; hp[3][1] = hv[7];
            #pragma unroll
            for (int u = 0; u < 4; u++) {
                #pragma unroll
                for (int j = 0; j < 4; j++) {
                    acc[j] = dot2f(wv[j][4 * i + u], hp[u], acc[j]);
                }
            }
        }
        part[s][4 * q + 0] = acc[0];
        part[s][4 * q + 1] = acc[1];
        part[s][4 * q + 2] = acc[2];
        part[s][4 * q + 3] = acc[3];
        __syncthreads();

        // ---- reduce 16 d-slices -> p[r], pack f16
        if (tid < RR) {
            float pv = 0.f;
            #pragma unroll
            for (int ss = 0; ss < 16; ss++) pv += part[ss][tid];
            pl[tid] = (f16)pv;
        }
        __syncthreads();

        // ---- stage 2: partial u over my r-half for 2 e's (p reads broadcast)
        const f16x8* psl = (const f16x8*)(pl + 128 * z);
        float ua[2] = {0.f, 0.f};
        #pragma unroll
        for (int i = 0; i < 16; i++) {
            f16x8 pv8 = psl[i];
            f16x2 pp[4];
            pp[0][0] = pv8[0]; pp[0][1] = pv8[1];
            pp[1][0] = pv8[2]; pp[1][1] = pv8[3];
            pp[2][0] = pv8[4]; pp[2][1] = pv8[5];
            pp[3][0] = pv8[6]; pp[3][1] = pv8[7];
            #pragma unroll
            for (int u = 0; u < 4; u++) {
                ua[0] = dot2f(wu[0][4 * i + u], pp[u], ua[0]);
                ua[1] = dot2f(wu[1][4 * i + u], pp[u], ua[1]);
            }
        }
        up[2 * e2 + 0][z] = ua[0];
        up[2 * e2 + 1][z] = ua[1];
        __syncthreads();

        // ---- elementwise: thread e = tid
        {
            float uu = up[tid][0] + up[tid][1] + (float)*wxp;
            float vv = tanh_f(uu);
            float aa = sigm_f((float)*axp);
            float hp = hf[tid];
            float hn = aa * hp + (1.0f - aa) * vv;
            float so = hn * hn * sigm_f(hn);   // h * silu(h)
            *outp  = so;
            *houtp = hn;
            hf[tid] = hn;
            h2[tid] = (f16)hn;
            axp += BB * DD; wxp += BB * DD; outp += BB * DD; houtp += BB * DD;
        }
        __syncthreads();   // h2/hf published before next stage 1
    }
}

extern "C" void kernel_launch(void* const* d_in, const int* in_sizes, int n_in,
                              void* d_out, int out_size, void* d_ws, size_t ws_size,
                              hipStream_t stream) {
    (void)in_sizes; (void)n_in; (void)out_size; (void)ws_size;
    const float* x  = (const float*)d_in[0];
    const float* h0 = (const float*)d_in[1];
    const float* Wa = (const float*)d_in[2];
    const float* ba = (const float*)d_in[3];
    const float* U  = (const float*)d_in[4];
    const float* V  = (const float*)d_in[5];
    const float* Wx = (const float*)d_in[6];
    const float* bb = (const float*)d_in[7];

    float* out  = (float*)d_out;                    // output [T,B,D]
    float* hout = out + (size_t)TT * BB * DD;       // h [T+1,B,D]

    f16* ax16 = (f16*)d_ws;                         // 64 MiB
    f16* wx16 = ax16 + (size_t)TT * BB * DD;        // 64 MiB

    dim3 g1(512, 16);   // m-tiles fastest: x (134MB) streams once per n-col, L3-resident
    fused_pregemm<<<g1, dim3(256), 0, stream>>>(x, Wa, Wx, ba, bb, ax16, wx16);
    rnn_scan<<<dim3(BB), dim3(1024), 0, stream>>>(ax16, wx16, V, U, h0, out, hout);
}